// Round 1
// baseline (416.666 us; speedup 1.0000x reference)
//
#include <hip/hip_runtime.h>
#include <math.h>

// Problem constants (match reference)
#define N_PTS 200000
#define M 32
#define P_INST 64
#define D 16
#define NP 337   // (D+3)*D + D + D + 1

#define BLK 256
#define RR 2                         // rows per thread in stats passes
#define ROWS_PER_BLK (BLK * RR)      // 512
#define NB_STATS ((N_PTS + ROWS_PER_BLK - 1) / ROWS_PER_BLK)  // 391
#define NB_FINAL ((N_PTS + BLK - 1) / BLK)                     // 782

// ws layout (floats):
//  [0, 21568)                params  (64 x 337)
//  [21568, 21760)            stats   (3 layers x {a[32], c[32]})
//  [21760, 21760 + NB*64)    per-block partial sums (sum[32], sumsq[32])
#define WS_PARAMS 0
#define WS_STATS  21568
#define WS_PART   21760

// ---------------------------------------------------------------------------
// Tiny kernel: embedding MLP + BN(P=64) + controller -> params[64][337]
// ---------------------------------------------------------------------------
__global__ __launch_bounds__(256) void k_params(
    const float* __restrict__ inst,    // 64 x 32
    const float* __restrict__ emb_w,   // 32 x 16
    const float* __restrict__ emb_g,   // 16
    const float* __restrict__ emb_b,   // 16
    const float* __restrict__ ctrl_w,  // 16 x 337
    const float* __restrict__ ctrl_b,  // 337
    float* __restrict__ params)        // 64 x 337
{
    __shared__ float sInst[P_INST * M];
    __shared__ float sE[P_INST * D];
    __shared__ float sA[D], sC[D];
    int t = threadIdx.x;

    for (int i = t; i < P_INST * M; i += 256) sInst[i] = inst[i];
    __syncthreads();

    // emb = inst @ emb_w  (64 x 16)
    for (int i = t; i < P_INST * D; i += 256) {
        int p = i >> 4, d = i & (D - 1);
        float acc = 0.f;
        #pragma unroll
        for (int k = 0; k < M; k++) acc = fmaf(sInst[p * M + k], emb_w[k * D + d], acc);
        sE[i] = acc;
    }
    __syncthreads();

    // BN over axis 0 (64 rows), per column d
    if (t < D) {
        float s = 0.f, q = 0.f;
        for (int p = 0; p < P_INST; p++) { float v = sE[p * D + t]; s += v; q += v * v; }
        float mu = s * (1.f / P_INST);
        float var = q * (1.f / P_INST) - mu * mu;
        float a = emb_g[t] * rsqrtf(var + 1e-5f);
        sA[t] = a;
        sC[t] = emb_b[t] - mu * a;
    }
    __syncthreads();

    for (int i = t; i < P_INST * D; i += 256) {
        int d = i & (D - 1);
        sE[i] = fmaxf(sE[i] * sA[d] + sC[d], 0.f);
    }
    __syncthreads();

    // params = e @ ctrl_w + ctrl_b   (64 x 337)
    for (int i = t; i < P_INST * NP; i += 256) {
        int p = i / NP, q = i - p * NP;
        float acc = ctrl_b[q];
        #pragma unroll
        for (int d = 0; d < D; d++) acc = fmaf(sE[p * D + d], ctrl_w[d * NP + q], acc);
        params[i] = acc;
    }
}

// ---------------------------------------------------------------------------
// Stats pass: recompute activations up to layer LAYERS, emit per-block
// partial (sum, sumsq) of the PRE-BN layer-LAYERS output.
// ---------------------------------------------------------------------------
template <int LAYERS>
__global__ __launch_bounds__(BLK) void k_stats(
    const float* __restrict__ feats,
    const float* __restrict__ w1, const float* __restrict__ w2, const float* __restrict__ w3,
    const float* __restrict__ stats,     // 3 x 64, only first LAYERS-1 read
    float* __restrict__ partials)        // NB x 64
{
    float sum[M], sq[M];
    #pragma unroll
    for (int j = 0; j < M; j++) { sum[j] = 0.f; sq[j] = 0.f; }
    int t = threadIdx.x;

    #pragma unroll 1
    for (int r = 0; r < RR; r++) {
        int row = blockIdx.x * ROWS_PER_BLK + r * BLK + t;
        if (row < N_PTS) {
            float x[M];
            const float4* fp = (const float4*)(feats + (size_t)row * M);
            #pragma unroll
            for (int q = 0; q < M / 4; q++) {
                float4 v = fp[q];
                x[4 * q] = v.x; x[4 * q + 1] = v.y; x[4 * q + 2] = v.z; x[4 * q + 3] = v.w;
            }
            #pragma unroll
            for (int l = 0; l < LAYERS; l++) {
                const float* W = (l == 0) ? w1 : ((l == 1) ? w2 : w3);
                float y[M];
                #pragma unroll
                for (int j = 0; j < M; j++) y[j] = 0.f;
                #pragma unroll
                for (int i = 0; i < M; i++) {
                    float xi = x[i];
                    #pragma unroll
                    for (int j = 0; j < M; j++) y[j] = fmaf(xi, W[i * M + j], y[j]);
                }
                if (l == LAYERS - 1) {
                    #pragma unroll
                    for (int j = 0; j < M; j++) { sum[j] += y[j]; sq[j] += y[j] * y[j]; }
                } else {
                    const float* st = stats + l * 64;
                    #pragma unroll
                    for (int j = 0; j < M; j++) x[j] = fmaxf(y[j] * st[j] + st[32 + j], 0.f);
                }
            }
        }
    }

    // wave(64) shuffle reduce, then cross-wave via LDS
    #pragma unroll
    for (int j = 0; j < M; j++) {
        #pragma unroll
        for (int off = 32; off; off >>= 1) {
            sum[j] += __shfl_down(sum[j], off, 64);
            sq[j]  += __shfl_down(sq[j],  off, 64);
        }
    }
    __shared__ float red[BLK / 64][64];
    int wave = t >> 6, lane = t & 63;
    if (lane == 0) {
        #pragma unroll
        for (int j = 0; j < M; j++) { red[wave][j] = sum[j]; red[wave][32 + j] = sq[j]; }
    }
    __syncthreads();
    if (t < 64) {
        float v = 0.f;
        #pragma unroll
        for (int w = 0; w < BLK / 64; w++) v += red[w][t];
        partials[(size_t)blockIdx.x * 64 + t] = v;
    }
}

// ---------------------------------------------------------------------------
// Reduce partials -> BN scale/shift (a = g*rsqrt(var+eps), c = b - mu*a)
// ---------------------------------------------------------------------------
__global__ __launch_bounds__(64) void k_reduce(
    const float* __restrict__ partials,
    const float* __restrict__ g, const float* __restrict__ b,
    float* __restrict__ stats_out)   // 64 floats: a[32], c[32]
{
    __shared__ float sh[64];
    int t = threadIdx.x;
    float s = 0.f;
    for (int i = 0; i < NB_STATS; i++) s += partials[(size_t)i * 64 + t];
    sh[t] = s;
    __syncthreads();
    if (t < 32) {
        float mu = sh[t] * (1.f / N_PTS);
        float var = sh[32 + t] * (1.f / N_PTS) - mu * mu;
        float a = g[t] * rsqrtf(var + 1e-5f);
        stats_out[t] = a;
        stats_out[32 + t] = b[t] - mu * a;
    }
}

// ---------------------------------------------------------------------------
// Final: recompute mask MLP -> mask_feats, then per-instance head -> logits
// Params indexed by uniform (p,const) -> compiler emits s_load; FMAs take the
// param as an SGPR operand (free).
// ---------------------------------------------------------------------------
__global__ __launch_bounds__(BLK) void k_final(
    const float* __restrict__ feats, const float* __restrict__ coords,
    const float* __restrict__ centers,
    const float* __restrict__ w1, const float* __restrict__ w2, const float* __restrict__ w3,
    const float* __restrict__ w_out, const float* __restrict__ b_out,
    const float* __restrict__ stats, const float* __restrict__ params,
    float* __restrict__ out)
{
    int n = blockIdx.x * BLK + threadIdx.x;
    if (n >= N_PTS) return;

    float x[M];
    const float4* fp = (const float4*)(feats + (size_t)n * M);
    #pragma unroll
    for (int q = 0; q < M / 4; q++) {
        float4 v = fp[q];
        x[4 * q] = v.x; x[4 * q + 1] = v.y; x[4 * q + 2] = v.z; x[4 * q + 3] = v.w;
    }

    #pragma unroll
    for (int l = 0; l < 3; l++) {
        const float* W = (l == 0) ? w1 : ((l == 1) ? w2 : w3);
        float y[M];
        #pragma unroll
        for (int j = 0; j < M; j++) y[j] = 0.f;
        #pragma unroll
        for (int i = 0; i < M; i++) {
            float xi = x[i];
            #pragma unroll
            for (int j = 0; j < M; j++) y[j] = fmaf(xi, W[i * M + j], y[j]);
        }
        const float* st = stats + l * 64;
        #pragma unroll
        for (int j = 0; j < M; j++) x[j] = fmaxf(y[j] * st[j] + st[32 + j], 0.f);
    }

    // mask_feats (16)
    float mf[D];
    #pragma unroll
    for (int d = 0; d < D; d++) mf[d] = b_out[d];
    #pragma unroll
    for (int i = 0; i < M; i++) {
        float xi = x[i];
        #pragma unroll
        for (int d = 0; d < D; d++) mf[d] = fmaf(xi, w_out[i * D + d], mf[d]);
    }

    float c0 = coords[(size_t)n * 3 + 0];
    float c1 = coords[(size_t)n * 3 + 1];
    float c2 = coords[(size_t)n * 3 + 2];

    #pragma unroll 1
    for (int p = 0; p < P_INST; p++) {
        const float* pp = params + p * NP;   // uniform -> s_load
        float rx = c0 - centers[p * 3 + 0];
        float ry = c1 - centers[p * 3 + 1];
        float rz = c2 - centers[p * 3 + 2];
        float acc = pp[336];                 // b2
        #pragma unroll
        for (int d = 0; d < D; d++) {
            float h = pp[320 + d];           // b1[d]
            h = fmaf(rx, pp[d * 19 + 0], h);
            h = fmaf(ry, pp[d * 19 + 1], h);
            h = fmaf(rz, pp[d * 19 + 2], h);
            #pragma unroll
            for (int k = 0; k < D; k++) h = fmaf(mf[k], pp[d * 19 + 3 + k], h);
            acc = fmaf(fmaxf(h, 0.f), pp[304 + d], acc);  // relu * w2
        }
        out[(size_t)p * N_PTS + n] = acc;
    }
}

// ---------------------------------------------------------------------------
extern "C" void kernel_launch(void* const* d_in, const int* in_sizes, int n_in,
                              void* d_out, int out_size, void* d_ws, size_t ws_size,
                              hipStream_t stream) {
    const float* feats   = (const float*)d_in[0];
    const float* coords  = (const float*)d_in[1];
    const float* inst    = (const float*)d_in[2];
    const float* centers = (const float*)d_in[3];
    const float* mw1 = (const float*)d_in[4];
    const float* mg1 = (const float*)d_in[5];
    const float* mb1 = (const float*)d_in[6];
    const float* mw2 = (const float*)d_in[7];
    const float* mg2 = (const float*)d_in[8];
    const float* mb2 = (const float*)d_in[9];
    const float* mw3 = (const float*)d_in[10];
    const float* mg3 = (const float*)d_in[11];
    const float* mb3 = (const float*)d_in[12];
    const float* wout = (const float*)d_in[13];
    const float* bout = (const float*)d_in[14];
    const float* embw = (const float*)d_in[15];
    const float* embg = (const float*)d_in[16];
    const float* embb = (const float*)d_in[17];
    const float* cw   = (const float*)d_in[18];
    const float* cb   = (const float*)d_in[19];

    float* wsf      = (float*)d_ws;
    float* params   = wsf + WS_PARAMS;
    float* stats    = wsf + WS_STATS;
    float* partials = wsf + WS_PART;
    float* out      = (float*)d_out;

    k_params<<<1, 256, 0, stream>>>(inst, embw, embg, embb, cw, cb, params);

    k_stats<1><<<NB_STATS, BLK, 0, stream>>>(feats, mw1, mw2, mw3, stats, partials);
    k_reduce<<<1, 64, 0, stream>>>(partials, mg1, mb1, stats + 0);

    k_stats<2><<<NB_STATS, BLK, 0, stream>>>(feats, mw1, mw2, mw3, stats, partials);
    k_reduce<<<1, 64, 0, stream>>>(partials, mg2, mb2, stats + 64);

    k_stats<3><<<NB_STATS, BLK, 0, stream>>>(feats, mw1, mw2, mw3, stats, partials);
    k_reduce<<<1, 64, 0, stream>>>(partials, mg3, mb3, stats + 128);

    k_final<<<NB_FINAL, BLK, 0, stream>>>(feats, coords, centers, mw1, mw2, mw3,
                                          wout, bout, stats, params, out);
}

// Round 2
// 359.932 us; speedup vs baseline: 1.1576x; 1.1576x over previous
//
#include <hip/hip_runtime.h>
#include <hip/hip_bf16.h>
#include <math.h>

#define N_PTS 200000
#define M 32
#define P_INST 64
#define D 16
#define NP 337

#define BLK 256
#define NB ((N_PTS + BLK - 1) / BLK)   // 782
#define SUM_BLOCKS 1024

// ws float-offset layout:
#define WS_PARAMS 0         // 64*337 = 21568
#define WS_STATS  21568     // 3*64 = 192  (per layer: a[32], c[32])
#define WS_W2     21760     // 64*16 = 1024
#define WS_B2     22784     // 64
#define WS_APACK  22912     // 64*512 bf16 = 16384 float-slots (MFMA A-frag order)
#define WS_PART   39296     // SUM_BLOCKS*64 = 65536
#define WS_Y      104832    // 200000*32 floats (25.6MB); Zb rows alias first 128B/row

typedef __attribute__((ext_vector_type(8))) short short8v;
typedef __attribute__((ext_vector_type(4))) float floatx4;

static __device__ __forceinline__ unsigned short f2bf(float v) {
    __hip_bfloat16 h = __float2bfloat16(v);
    return *reinterpret_cast<unsigned short*>(&h);
}

// ---------------------------------------------------------------------------
// params = ctrl head on 64 instances (tiny, 1 block)
// ---------------------------------------------------------------------------
__global__ __launch_bounds__(256) void k_params(
    const float* __restrict__ inst, const float* __restrict__ emb_w,
    const float* __restrict__ emb_g, const float* __restrict__ emb_b,
    const float* __restrict__ ctrl_w, const float* __restrict__ ctrl_b,
    float* __restrict__ params)
{
    __shared__ float sInst[P_INST * M];
    __shared__ float sE[P_INST * D];
    __shared__ float sA[D], sC[D];
    int t = threadIdx.x;

    for (int i = t; i < P_INST * M; i += 256) sInst[i] = inst[i];
    __syncthreads();

    for (int i = t; i < P_INST * D; i += 256) {
        int p = i >> 4, d = i & (D - 1);
        float acc = 0.f;
        #pragma unroll
        for (int k = 0; k < M; k++) acc = fmaf(sInst[p * M + k], emb_w[k * D + d], acc);
        sE[i] = acc;
    }
    __syncthreads();

    if (t < D) {
        float s = 0.f, q = 0.f;
        for (int p = 0; p < P_INST; p++) { float v = sE[p * D + t]; s += v; q += v * v; }
        float mu = s * (1.f / P_INST);
        float var = q * (1.f / P_INST) - mu * mu;
        float a = emb_g[t] * rsqrtf(var + 1e-5f);
        sA[t] = a;
        sC[t] = emb_b[t] - mu * a;
    }
    __syncthreads();

    for (int i = t; i < P_INST * D; i += 256) {
        int d = i & (D - 1);
        sE[i] = fmaxf(sE[i] * sA[d] + sC[d], 0.f);
    }
    __syncthreads();

    for (int i = t; i < P_INST * NP; i += 256) {
        int p = i / NP, q = i - p * NP;
        float acc = ctrl_b[q];
        #pragma unroll
        for (int d = 0; d < D; d++) acc = fmaf(sE[p * D + d], ctrl_w[d * NP + q], acc);
        params[i] = acc;
    }
}

// ---------------------------------------------------------------------------
// Pack per-p head weights into MFMA A-fragment order (bf16), fold centers
// into the bias K-row.  A~[d][k]: k<19 -> w1, k==19 -> b1 - centers.w1[:,:3]
// Lane l holds A~[l&15][(l>>4)*8 + j], j=0..7 (16B contiguous per lane).
// ---------------------------------------------------------------------------
__global__ __launch_bounds__(64) void k_pack(
    const float* __restrict__ params, const float* __restrict__ centers,
    float* __restrict__ apackf, float* __restrict__ w2p, float* __restrict__ b2p)
{
    int p = blockIdx.x;
    int l = threadIdx.x;
    const float* pp = params + p * NP;
    int row = l & 15, kbase = (l >> 4) * 8;

    unsigned int w[4];
    #pragma unroll
    for (int i = 0; i < 4; i++) {
        unsigned short lo, hi;
        #pragma unroll
        for (int h = 0; h < 2; h++) {
            int k = kbase + 2 * i + h;
            float v;
            if (k < 19) v = pp[row * 19 + k];
            else if (k == 19)
                v = pp[320 + row] - (centers[p * 3 + 0] * pp[row * 19 + 0]
                                   + centers[p * 3 + 1] * pp[row * 19 + 1]
                                   + centers[p * 3 + 2] * pp[row * 19 + 2]);
            else v = 0.f;
            if (h == 0) lo = f2bf(v); else hi = f2bf(v);
        }
        w[i] = (unsigned)lo | ((unsigned)hi << 16);
    }
    uint4* dst = (uint4*)((char*)apackf + (size_t)p * 1024 + l * 16);
    *dst = make_uint4(w[0], w[1], w[2], w[3]);

    if (l < 16) w2p[p * 16 + l] = pp[304 + l];
    if (l == 0) b2p[p] = pp[336];
}

// ---------------------------------------------------------------------------
// One MLP layer: (optional BN+relu of prev layer) then x @ W -> ybuf (in-place
// row-local).  W reads are lane-uniform -> s_load, free SGPR operands.
// ---------------------------------------------------------------------------
template <int L>
__global__ __launch_bounds__(BLK) void k_layer(
    const float* __restrict__ feats, const float* __restrict__ W,
    const float* __restrict__ stats, float* __restrict__ ybuf)
{
    int n = blockIdx.x * BLK + threadIdx.x;
    if (n >= N_PTS) return;

    const float* src = (L == 0) ? (feats + (size_t)n * M) : (ybuf + (size_t)n * M);
    float x[M];
    #pragma unroll
    for (int q = 0; q < M / 4; q++) {
        float4 v = ((const float4*)src)[q];
        x[4*q] = v.x; x[4*q+1] = v.y; x[4*q+2] = v.z; x[4*q+3] = v.w;
    }
    if (L > 0) {
        const float* st = stats + (L - 1) * 64;
        #pragma unroll
        for (int j = 0; j < M; j++) x[j] = fmaxf(fmaf(x[j], st[j], st[32 + j]), 0.f);
    }
    float y[M];
    #pragma unroll
    for (int j = 0; j < M; j++) y[j] = 0.f;
    #pragma unroll
    for (int i = 0; i < M; i++) {
        float xi = x[i];
        #pragma unroll
        for (int j = 0; j < M; j++) y[j] = fmaf(xi, W[i * M + j], y[j]);
    }
    float4* dst = (float4*)(ybuf + (size_t)n * M);
    #pragma unroll
    for (int q = 0; q < M / 4; q++)
        dst[q] = make_float4(y[4*q], y[4*q+1], y[4*q+2], y[4*q+3]);
}

// ---------------------------------------------------------------------------
// BW-bound column sums of ybuf -> per-block partials (sum & sumsq, 32 ch)
// thread's channel group g = t&7 (4 channels via float4)
// ---------------------------------------------------------------------------
__global__ __launch_bounds__(BLK) void k_sum(
    const float* __restrict__ ybuf, float* __restrict__ partials)
{
    int t = threadIdx.x;
    int g = t & 7;
    float s[4] = {0.f, 0.f, 0.f, 0.f}, q[4] = {0.f, 0.f, 0.f, 0.f};

    for (long long idx = blockIdx.x * (long long)BLK + t; (idx >> 3) < N_PTS;
         idx += (long long)SUM_BLOCKS * BLK) {
        long long row = idx >> 3;
        float4 v = *(const float4*)(ybuf + row * M + g * 4);
        s[0] += v.x; s[1] += v.y; s[2] += v.z; s[3] += v.w;
        q[0] += v.x * v.x; q[1] += v.y * v.y; q[2] += v.z * v.z; q[3] += v.w * v.w;
    }
    #pragma unroll
    for (int i = 0; i < 4; i++) {
        #pragma unroll
        for (int off = 32; off >= 8; off >>= 1) {
            s[i] += __shfl_down(s[i], off, 64);
            q[i] += __shfl_down(q[i], off, 64);
        }
    }
    __shared__ float red[BLK / 64][64];
    int wv = t >> 6, lane = t & 63;
    if (lane < 8) {
        #pragma unroll
        for (int i = 0; i < 4; i++) {
            red[wv][lane * 8 + i] = s[i];
            red[wv][lane * 8 + 4 + i] = q[i];
        }
    }
    __syncthreads();
    if (t < 64)
        partials[(size_t)blockIdx.x * 64 + t] =
            red[0][t] + red[1][t] + red[2][t] + red[3][t];
}

// partial index j = g*8 + i ; channel = g*4 + (i&3) ; kind = i>>2
__global__ __launch_bounds__(256) void k_reduce(
    const float* __restrict__ partials,
    const float* __restrict__ g, const float* __restrict__ b,
    float* __restrict__ stats_out)
{
    __shared__ float sh[4][64];
    int t = threadIdx.x, j = t & 63, c = t >> 6;
    float s = 0.f;
    for (int i = c; i < SUM_BLOCKS; i += 4) s += partials[(size_t)i * 64 + j];
    sh[c][j] = s;
    __syncthreads();
    if (t < 64) sh[0][t] = sh[0][t] + sh[1][t] + sh[2][t] + sh[3][t];
    __syncthreads();
    if (t < 32) {
        int js = (t >> 2) * 8 + (t & 3);
        float S = sh[0][js], Q = sh[0][js + 4];
        float mu = S * (1.f / N_PTS);
        float var = Q * (1.f / N_PTS) - mu * mu;
        float a = g[t] * rsqrtf(var + 1e-5f);
        stats_out[t] = a;
        stats_out[32 + t] = b[t] - mu * a;
    }
}

// ---------------------------------------------------------------------------
// BN3+relu -> mask_feats -> pack Z[n] = [c0,c1,c2, mf0..15, 1, 0..] as bf16
// into the FIRST 128B of each ybuf row (in-place, row-local).
// ---------------------------------------------------------------------------
__global__ __launch_bounds__(BLK) void k_z(
    const float* __restrict__ coords, const float* __restrict__ w_out,
    const float* __restrict__ b_out, const float* __restrict__ stats,
    float* __restrict__ ybuf)
{
    int n = blockIdx.x * BLK + threadIdx.x;
    if (n >= N_PTS) return;
    float* yr = ybuf + (size_t)n * M;
    float x[M];
    #pragma unroll
    for (int q = 0; q < M / 4; q++) {
        float4 v = ((const float4*)yr)[q];
        x[4*q] = v.x; x[4*q+1] = v.y; x[4*q+2] = v.z; x[4*q+3] = v.w;
    }
    const float* st = stats + 128;
    #pragma unroll
    for (int j = 0; j < M; j++) x[j] = fmaxf(fmaf(x[j], st[j], st[32 + j]), 0.f);

    float mf[D];
    #pragma unroll
    for (int d = 0; d < D; d++) mf[d] = b_out[d];
    #pragma unroll
    for (int i = 0; i < M; i++) {
        float xi = x[i];
        #pragma unroll
        for (int d = 0; d < D; d++) mf[d] = fmaf(xi, w_out[i * D + d], mf[d]);
    }
    float z[32];
    z[0] = coords[(size_t)n * 3 + 0];
    z[1] = coords[(size_t)n * 3 + 1];
    z[2] = coords[(size_t)n * 3 + 2];
    #pragma unroll
    for (int d = 0; d < D; d++) z[3 + d] = mf[d];
    z[19] = 1.0f;
    #pragma unroll
    for (int k = 20; k < 32; k++) z[k] = 0.f;

    unsigned int zw[16];
    #pragma unroll
    for (int i = 0; i < 16; i++)
        zw[i] = (unsigned)f2bf(z[2 * i]) | ((unsigned)f2bf(z[2 * i + 1]) << 16);
    uint4* dst = (uint4*)yr;
    #pragma unroll
    for (int i = 0; i < 4; i++)
        dst[i] = make_uint4(zw[4*i], zw[4*i+1], zw[4*i+2], zw[4*i+3]);
}

// ---------------------------------------------------------------------------
// Head: per wave, 64 points (4 x 16-col B-frags); loop p: 1 A-frag load,
// 4 MFMA, relu.w2 epilogue, masked 16-lane store.
// ---------------------------------------------------------------------------
__global__ __launch_bounds__(BLK) void k_head(
    const float* __restrict__ ybuf, const float* __restrict__ w2p,
    const float* __restrict__ b2p, const float* __restrict__ apackf,
    float* __restrict__ out)
{
    int t = threadIdx.x;
    int lane = t & 63, wv = t >> 6;
    int n0 = blockIdx.x * 256 + wv * 64;
    int cl = lane & 15, kg = lane >> 4;

    const char* zbase = (const char*)ybuf;
    short8v b8[4];
    #pragma unroll
    for (int s = 0; s < 4; s++) {
        int nn = n0 + s * 16 + cl;
        int nc = nn < N_PTS ? nn : 0;
        b8[s] = *(const short8v*)(zbase + (size_t)nc * 128 + kg * 16);
    }
    const char* abase = (const char*)apackf;

    #pragma unroll 1
    for (int p = 0; p < P_INST; p++) {
        short8v a8 = *(const short8v*)(abase + (size_t)p * 1024 + lane * 16);
        floatx4 w2v = *(const floatx4*)(w2p + p * 16 + kg * 4);
        float b2 = b2p[p];
        #pragma unroll
        for (int s = 0; s < 4; s++) {
            floatx4 acc = {0.f, 0.f, 0.f, 0.f};
            acc = __builtin_amdgcn_mfma_f32_16x16x32_bf16(a8, b8[s], acc, 0, 0, 0);
            float v = fmaxf(acc[0], 0.f) * w2v[0];
            v = fmaf(fmaxf(acc[1], 0.f), w2v[1], v);
            v = fmaf(fmaxf(acc[2], 0.f), w2v[2], v);
            v = fmaf(fmaxf(acc[3], 0.f), w2v[3], v);
            v += __shfl_xor(v, 16, 64);
            v += __shfl_xor(v, 32, 64);
            int nn = n0 + s * 16 + cl;
            if (lane < 16 && nn < N_PTS)
                out[(size_t)p * N_PTS + nn] = v + b2;
        }
    }
}

// ---------------------------------------------------------------------------
extern "C" void kernel_launch(void* const* d_in, const int* in_sizes, int n_in,
                              void* d_out, int out_size, void* d_ws, size_t ws_size,
                              hipStream_t stream) {
    const float* feats   = (const float*)d_in[0];
    const float* coords  = (const float*)d_in[1];
    const float* inst    = (const float*)d_in[2];
    const float* centers = (const float*)d_in[3];
    const float* mw1 = (const float*)d_in[4];
    const float* mg1 = (const float*)d_in[5];
    const float* mb1 = (const float*)d_in[6];
    const float* mw2 = (const float*)d_in[7];
    const float* mg2 = (const float*)d_in[8];
    const float* mb2 = (const float*)d_in[9];
    const float* mw3 = (const float*)d_in[10];
    const float* mg3 = (const float*)d_in[11];
    const float* mb3 = (const float*)d_in[12];
    const float* wout = (const float*)d_in[13];
    const float* bout = (const float*)d_in[14];
    const float* embw = (const float*)d_in[15];
    const float* embg = (const float*)d_in[16];
    const float* embb = (const float*)d_in[17];
    const float* cw   = (const float*)d_in[18];
    const float* cb   = (const float*)d_in[19];

    float* wsf      = (float*)d_ws;
    float* params   = wsf + WS_PARAMS;
    float* stats    = wsf + WS_STATS;
    float* w2p      = wsf + WS_W2;
    float* b2p      = wsf + WS_B2;
    float* apackf   = wsf + WS_APACK;
    float* partials = wsf + WS_PART;
    float* ybuf     = wsf + WS_Y;
    float* out      = (float*)d_out;

    k_params<<<1, 256, 0, stream>>>(inst, embw, embg, embb, cw, cb, params);
    k_pack<<<P_INST, 64, 0, stream>>>(params, centers, apackf, w2p, b2p);

    k_layer<0><<<NB, BLK, 0, stream>>>(feats, mw1, stats, ybuf);
    k_sum<<<SUM_BLOCKS, BLK, 0, stream>>>(ybuf, partials);
    k_reduce<<<1, 256, 0, stream>>>(partials, mg1, mb1, stats + 0);

    k_layer<1><<<NB, BLK, 0, stream>>>(feats, mw2, stats, ybuf);
    k_sum<<<SUM_BLOCKS, BLK, 0, stream>>>(ybuf, partials);
    k_reduce<<<1, 256, 0, stream>>>(partials, mg2, mb2, stats + 64);

    k_layer<2><<<NB, BLK, 0, stream>>>(feats, mw3, stats, ybuf);
    k_sum<<<SUM_BLOCKS, BLK, 0, stream>>>(ybuf, partials);
    k_reduce<<<1, 256, 0, stream>>>(partials, mg3, mb3, stats + 128);

    k_z<<<NB, BLK, 0, stream>>>(coords, wout, bout, stats, ybuf);

    k_head<<<NB, BLK, 0, stream>>>(ybuf, w2p, b2p, apackf, out);
}

// Round 3
// 203.798 us; speedup vs baseline: 2.0445x; 1.7661x over previous
//
#include <hip/hip_runtime.h>
#include <hip/hip_bf16.h>
#include <math.h>

#define N_PTS 200000
#define M 32
#define P_INST 64
#define D 16
#define NP 337

#define BLK 256
#define NB ((N_PTS + BLK - 1) / BLK)   // 782
#define SUM_BLOCKS 1024

// ws float-offset layout:
#define WS_PARAMS 0         // 64*337 = 21568
#define WS_STATS  21568     // 3*64 (per layer: a[32], c[32])
#define WS_W2     21760     // 64*16
#define WS_B2     22784     // 64
#define WS_APACK  22912     // 64*512 bf16 = 16384 float-slots
#define WS_PART   39296     // SUM_BLOCKS*64 = 65536
#define WS_Y      104832    // 200000*32 floats (25.6MB)

typedef __attribute__((ext_vector_type(8))) short short8v;
typedef __attribute__((ext_vector_type(4))) float floatx4;

static __device__ __forceinline__ unsigned short f2bf(float v) {
    __hip_bfloat16 h = __float2bfloat16(v);
    return *reinterpret_cast<unsigned short*>(&h);
}

// ---------------------------------------------------------------------------
// k_prep: embedding MLP + BN(64) + controller -> params, then pack A-frags
// (bf16, centers folded into bias K-row), w2, b2.  One block.
// ---------------------------------------------------------------------------
__global__ __launch_bounds__(256) void k_prep(
    const float* __restrict__ inst, const float* __restrict__ emb_w,
    const float* __restrict__ emb_g, const float* __restrict__ emb_b,
    const float* __restrict__ ctrl_w, const float* __restrict__ ctrl_b,
    const float* __restrict__ centers,
    float* __restrict__ params, float* __restrict__ apackf,
    float* __restrict__ w2p, float* __restrict__ b2p)
{
    __shared__ float sInst[P_INST * M];
    __shared__ float sE[P_INST * D];
    __shared__ float sCW[D * NP];       // 21.6 KB
    __shared__ float sA[D], sC[D];
    int t = threadIdx.x;

    for (int i = t; i < P_INST * M; i += 256) sInst[i] = inst[i];
    for (int i = t; i < D * NP; i += 256) sCW[i] = ctrl_w[i];
    __syncthreads();

    for (int i = t; i < P_INST * D; i += 256) {
        int p = i >> 4, d = i & (D - 1);
        float acc = 0.f;
        #pragma unroll
        for (int k = 0; k < M; k++) acc = fmaf(sInst[p * M + k], emb_w[k * D + d], acc);
        sE[i] = acc;
    }
    __syncthreads();

    if (t < D) {
        float s = 0.f, q = 0.f;
        for (int p = 0; p < P_INST; p++) { float v = sE[p * D + t]; s += v; q += v * v; }
        float mu = s * (1.f / P_INST);
        float var = q * (1.f / P_INST) - mu * mu;
        float a = emb_g[t] * rsqrtf(var + 1e-5f);
        sA[t] = a;
        sC[t] = emb_b[t] - mu * a;
    }
    __syncthreads();

    for (int i = t; i < P_INST * D; i += 256) {
        int d = i & (D - 1);
        sE[i] = fmaxf(sE[i] * sA[d] + sC[d], 0.f);
    }
    __syncthreads();

    for (int i = t; i < P_INST * NP; i += 256) {
        int p = i / NP, q = i - p * NP;
        float acc = ctrl_b[q];
        #pragma unroll
        for (int d = 0; d < D; d++) acc = fmaf(sE[p * D + d], sCW[d * NP + q], acc);
        params[i] = acc;
    }
    __threadfence_block();
    __syncthreads();

    // pack: lane l of wave wv packs A-frag rows for p = wv, wv+4, ...
    int lane = t & 63, wv = t >> 6;
    int row = lane & 15, kbase = (lane >> 4) * 8;
    for (int p = wv; p < P_INST; p += 4) {
        const float* pp = params + p * NP;
        unsigned int w[4];
        #pragma unroll
        for (int i = 0; i < 4; i++) {
            unsigned short lo = 0, hi = 0;
            #pragma unroll
            for (int h = 0; h < 2; h++) {
                int k = kbase + 2 * i + h;
                float v;
                if (k < 19) v = pp[row * 19 + k];
                else if (k == 19)
                    v = pp[320 + row] - (centers[p * 3 + 0] * pp[row * 19 + 0]
                                       + centers[p * 3 + 1] * pp[row * 19 + 1]
                                       + centers[p * 3 + 2] * pp[row * 19 + 2]);
                else v = 0.f;
                if (h == 0) lo = f2bf(v); else hi = f2bf(v);
            }
            w[i] = (unsigned)lo | ((unsigned)hi << 16);
        }
        uint4* dst = (uint4*)((char*)apackf + (size_t)p * 1024 + lane * 16);
        *dst = make_uint4(w[0], w[1], w[2], w[3]);
        if (lane < 16) w2p[p * 16 + lane] = pp[304 + lane];
        if (lane == 0) b2p[p] = pp[336];
    }
}

// ---------------------------------------------------------------------------
// One MLP layer: (optional BN+relu of prev) then x @ W -> ybuf (row-local)
// ---------------------------------------------------------------------------
template <int L>
__global__ __launch_bounds__(BLK) void k_layer(
    const float* __restrict__ feats, const float* __restrict__ W,
    const float* __restrict__ stats, float* __restrict__ ybuf)
{
    int n = blockIdx.x * BLK + threadIdx.x;
    if (n >= N_PTS) return;

    const float* src = (L == 0) ? (feats + (size_t)n * M) : (ybuf + (size_t)n * M);
    float x[M];
    #pragma unroll
    for (int q = 0; q < M / 4; q++) {
        float4 v = ((const float4*)src)[q];
        x[4*q] = v.x; x[4*q+1] = v.y; x[4*q+2] = v.z; x[4*q+3] = v.w;
    }
    if (L > 0) {
        const float* st = stats + (L - 1) * 64;
        #pragma unroll
        for (int j = 0; j < M; j++) x[j] = fmaxf(fmaf(x[j], st[j], st[32 + j]), 0.f);
    }
    float y[M];
    #pragma unroll
    for (int j = 0; j < M; j++) y[j] = 0.f;
    #pragma unroll
    for (int i = 0; i < M; i++) {
        float xi = x[i];
        #pragma unroll
        for (int j = 0; j < M; j++) y[j] = fmaf(xi, W[i * M + j], y[j]);
    }
    float4* dst = (float4*)(ybuf + (size_t)n * M);
    #pragma unroll
    for (int q = 0; q < M / 4; q++)
        dst[q] = make_float4(y[4*q], y[4*q+1], y[4*q+2], y[4*q+3]);
}

// ---------------------------------------------------------------------------
// Column sums of ybuf -> partials[bid][j]  (j<32: sum ch j, j>=32: sumsq)
// ---------------------------------------------------------------------------
__global__ __launch_bounds__(BLK) void k_sum(
    const float* __restrict__ ybuf, float* __restrict__ partials)
{
    int t = threadIdx.x;
    int g = t & 7;
    float s[4] = {0.f, 0.f, 0.f, 0.f}, q[4] = {0.f, 0.f, 0.f, 0.f};

    for (long long idx = blockIdx.x * (long long)BLK + t; (idx >> 3) < N_PTS;
         idx += (long long)SUM_BLOCKS * BLK) {
        long long row = idx >> 3;
        float4 v = *(const float4*)(ybuf + row * M + g * 4);
        s[0] += v.x; s[1] += v.y; s[2] += v.z; s[3] += v.w;
        q[0] += v.x * v.x; q[1] += v.y * v.y; q[2] += v.z * v.z; q[3] += v.w * v.w;
    }
    #pragma unroll
    for (int i = 0; i < 4; i++) {
        #pragma unroll
        for (int off = 32; off >= 8; off >>= 1) {
            s[i] += __shfl_down(s[i], off, 64);
            q[i] += __shfl_down(q[i], off, 64);
        }
    }
    __shared__ float red[BLK / 64][64];
    int wv = t >> 6, lane = t & 63;
    if (lane < 8) {   // lane == g, holds totals for channels lane*4..lane*4+3
        #pragma unroll
        for (int i = 0; i < 4; i++) {
            red[wv][lane * 4 + i] = s[i];
            red[wv][32 + lane * 4 + i] = q[i];
        }
    }
    __syncthreads();
    if (t < 64)
        partials[(size_t)blockIdx.x * 64 + t] =
            red[0][t] + red[1][t] + red[2][t] + red[3][t];
}

// ---------------------------------------------------------------------------
// Parallel reduce: block c handles channel c; 128 threads sum, 128 sumsq
// ---------------------------------------------------------------------------
__global__ __launch_bounds__(256) void k_reduce(
    const float* __restrict__ partials,
    const float* __restrict__ g, const float* __restrict__ b,
    float* __restrict__ stats_out)
{
    int c = blockIdx.x;          // 0..31
    int t = threadIdx.x;
    int part = t >> 7;           // 0: sum, 1: sumsq
    int i0 = t & 127;
    float s = 0.f;
    for (int i = i0; i < SUM_BLOCKS; i += 128)
        s += partials[(size_t)i * 64 + c + part * 32];
    __shared__ float sh[256];
    sh[t] = s;
    __syncthreads();
    #pragma unroll
    for (int off = 64; off; off >>= 1) {
        if ((t & 127) < off) sh[t] += sh[t + off];
        __syncthreads();
    }
    if (t == 0) {
        float S = sh[0], Q = sh[128];
        float mu = S * (1.f / N_PTS);
        float var = Q * (1.f / N_PTS) - mu * mu;
        float a = g[c] * rsqrtf(var + 1e-5f);
        stats_out[c] = a;
        stats_out[32 + c] = b[c] - mu * a;
    }
}

// ---------------------------------------------------------------------------
// Fused head: BN3+relu -> mask_feats -> Z pack (LDS, stride 80B) -> per-p
// MFMA h = Z @ A~p^T, relu, dot w2, store logits.
// ---------------------------------------------------------------------------
__global__ __launch_bounds__(BLK) void k_head(
    const float* __restrict__ ybuf, const float* __restrict__ coords,
    const float* __restrict__ w_out, const float* __restrict__ b_out,
    const float* __restrict__ stats, const float* __restrict__ w2p,
    const float* __restrict__ b2p, const float* __restrict__ apackf,
    float* __restrict__ out)
{
    __shared__ unsigned int zlds[BLK * 20];   // 80B per point (pad for banks)
    int t = threadIdx.x;
    int nblk = blockIdx.x * BLK;
    int nc = nblk + t;
    if (nc >= N_PTS) nc = N_PTS - 1;

    // ---- phase 1: Z for point nc ----
    const float* yr = ybuf + (size_t)nc * M;
    float x[M];
    #pragma unroll
    for (int q = 0; q < M / 4; q++) {
        float4 v = ((const float4*)yr)[q];
        x[4*q] = v.x; x[4*q+1] = v.y; x[4*q+2] = v.z; x[4*q+3] = v.w;
    }
    const float* st = stats + 128;
    #pragma unroll
    for (int j = 0; j < M; j++) x[j] = fmaxf(fmaf(x[j], st[j], st[32 + j]), 0.f);

    float mf[D];
    #pragma unroll
    for (int d = 0; d < D; d++) mf[d] = b_out[d];
    #pragma unroll
    for (int i = 0; i < M; i++) {
        float xi = x[i];
        #pragma unroll
        for (int d = 0; d < D; d++) mf[d] = fmaf(xi, w_out[i * D + d], mf[d]);
    }
    float z[20];
    z[0] = coords[(size_t)nc * 3 + 0];
    z[1] = coords[(size_t)nc * 3 + 1];
    z[2] = coords[(size_t)nc * 3 + 2];
    #pragma unroll
    for (int d = 0; d < D; d++) z[3 + d] = mf[d];
    z[19] = 1.0f;

    unsigned int zw[16];
    #pragma unroll
    for (int i = 0; i < 10; i++)
        zw[i] = (unsigned)f2bf(z[2 * i]) | ((unsigned)f2bf(z[2 * i + 1]) << 16);
    #pragma unroll
    for (int i = 10; i < 16; i++) zw[i] = 0u;
    uint4* zd = (uint4*)&zlds[t * 20];
    #pragma unroll
    for (int i = 0; i < 4; i++)
        zd[i] = make_uint4(zw[4*i], zw[4*i+1], zw[4*i+2], zw[4*i+3]);
    __syncthreads();

    // ---- phase 2: MFMA over p ----
    int lane = t & 63, wv = t >> 6;
    int cl = lane & 15, kg = lane >> 4;
    int n0 = nblk + wv * 64;

    short8v b8[4];
    #pragma unroll
    for (int s = 0; s < 4; s++)
        b8[s] = *(const short8v*)&zlds[(wv * 64 + s * 16 + cl) * 20 + kg * 4];

    const char* abase = (const char*)apackf;
    #pragma unroll 1
    for (int p = 0; p < P_INST; p++) {
        short8v a8 = *(const short8v*)(abase + (size_t)p * 1024 + lane * 16);
        floatx4 w2v = *(const floatx4*)(w2p + p * 16 + kg * 4);
        float b2 = b2p[p];
        #pragma unroll
        for (int s = 0; s < 4; s++) {
            floatx4 acc = {0.f, 0.f, 0.f, 0.f};
            acc = __builtin_amdgcn_mfma_f32_16x16x32_bf16(a8, b8[s], acc, 0, 0, 0);
            float v = fmaxf(acc[0], 0.f) * w2v[0];
            v = fmaf(fmaxf(acc[1], 0.f), w2v[1], v);
            v = fmaf(fmaxf(acc[2], 0.f), w2v[2], v);
            v = fmaf(fmaxf(acc[3], 0.f), w2v[3], v);
            v += __shfl_xor(v, 16, 64);
            v += __shfl_xor(v, 32, 64);
            int nn = n0 + s * 16 + cl;
            if (lane < 16 && nn < N_PTS)
                out[(size_t)p * N_PTS + nn] = v + b2;
        }
    }
}

// ---------------------------------------------------------------------------
extern "C" void kernel_launch(void* const* d_in, const int* in_sizes, int n_in,
                              void* d_out, int out_size, void* d_ws, size_t ws_size,
                              hipStream_t stream) {
    const float* feats   = (const float*)d_in[0];
    const float* coords  = (const float*)d_in[1];
    const float* inst    = (const float*)d_in[2];
    const float* centers = (const float*)d_in[3];
    const float* mw1 = (const float*)d_in[4];
    const float* mg1 = (const float*)d_in[5];
    const float* mb1 = (const float*)d_in[6];
    const float* mw2 = (const float*)d_in[7];
    const float* mg2 = (const float*)d_in[8];
    const float* mb2 = (const float*)d_in[9];
    const float* mw3 = (const float*)d_in[10];
    const float* mg3 = (const float*)d_in[11];
    const float* mb3 = (const float*)d_in[12];
    const float* wout = (const float*)d_in[13];
    const float* bout = (const float*)d_in[14];
    const float* embw = (const float*)d_in[15];
    const float* embg = (const float*)d_in[16];
    const float* embb = (const float*)d_in[17];
    const float* cw   = (const float*)d_in[18];
    const float* cb   = (const float*)d_in[19];

    float* wsf      = (float*)d_ws;
    float* params   = wsf + WS_PARAMS;
    float* stats    = wsf + WS_STATS;
    float* w2p      = wsf + WS_W2;
    float* b2p      = wsf + WS_B2;
    float* apackf   = wsf + WS_APACK;
    float* partials = wsf + WS_PART;
    float* ybuf     = wsf + WS_Y;
    float* out      = (float*)d_out;

    k_prep<<<1, 256, 0, stream>>>(inst, embw, embg, embb, cw, cb, centers,
                                  params, apackf, w2p, b2p);

    k_layer<0><<<NB, BLK, 0, stream>>>(feats, mw1, stats, ybuf);
    k_sum<<<SUM_BLOCKS, BLK, 0, stream>>>(ybuf, partials);
    k_reduce<<<32, 256, 0, stream>>>(partials, mg1, mb1, stats + 0);

    k_layer<1><<<NB, BLK, 0, stream>>>(feats, mw2, stats, ybuf);
    k_sum<<<SUM_BLOCKS, BLK, 0, stream>>>(ybuf, partials);
    k_reduce<<<32, 256, 0, stream>>>(partials, mg2, mb2, stats + 64);

    k_layer<2><<<NB, BLK, 0, stream>>>(feats, mw3, stats, ybuf);
    k_sum<<<SUM_BLOCKS, BLK, 0, stream>>>(ybuf, partials);
    k_reduce<<<32, 256, 0, stream>>>(partials, mg3, mb3, stats + 128);

    k_head<<<NB, BLK, 0, stream>>>(ybuf, coords, wout, bout, stats,
                                   w2p, b2p, apackf, out);
}

// Round 4
// 178.122 us; speedup vs baseline: 2.3392x; 1.1441x over previous
//
#include <hip/hip_runtime.h>
#include <hip/hip_bf16.h>
#include <math.h>

#define N_PTS 200000
#define M 32
#define P_INST 64
#define D 16
#define NP 337

#define BLK 256
#define NB ((N_PTS + BLK - 1) / BLK)   // 782 (layer blocks; also #partials)
#define HPB 128                        // points per head block
#define NBH ((N_PTS + HPB - 1) / HPB)  // 1563

// ws float-offset layout:
#define WS_PARAMS 0         // 64*337 = 21568
#define WS_STATS  21568     // 3*64 (per layer: a[32], c[32])
#define WS_W2     21760     // 64*16
#define WS_B2     22784     // 64
#define WS_APACK  22912     // 64*512 bf16 = 16384 float-slots
#define WS_PART   39296     // NB*64 = 50048 used
#define WS_Y      104832    // 200000*32 floats (25.6MB)

typedef __attribute__((ext_vector_type(8))) short short8v;
typedef __attribute__((ext_vector_type(4))) float floatx4;

static __device__ __forceinline__ unsigned short f2bf(float v) {
    __hip_bfloat16 h = __float2bfloat16(v);
    return *reinterpret_cast<unsigned short*>(&h);
}

// ---------------------------------------------------------------------------
// k_prep: embedding MLP + BN(64) + controller -> params, then pack A-frags
// (bf16, centers folded into bias K-row), w2, b2.  One block.
// ---------------------------------------------------------------------------
__global__ __launch_bounds__(256) void k_prep(
    const float* __restrict__ inst, const float* __restrict__ emb_w,
    const float* __restrict__ emb_g, const float* __restrict__ emb_b,
    const float* __restrict__ ctrl_w, const float* __restrict__ ctrl_b,
    const float* __restrict__ centers,
    float* __restrict__ params, float* __restrict__ apackf,
    float* __restrict__ w2p, float* __restrict__ b2p)
{
    __shared__ float sInst[P_INST * M];
    __shared__ float sE[P_INST * D];
    __shared__ float sCW[D * NP];
    __shared__ float sA[D], sC[D];
    int t = threadIdx.x;

    for (int i = t; i < P_INST * M; i += 256) sInst[i] = inst[i];
    for (int i = t; i < D * NP; i += 256) sCW[i] = ctrl_w[i];
    __syncthreads();

    for (int i = t; i < P_INST * D; i += 256) {
        int p = i >> 4, d = i & (D - 1);
        float acc = 0.f;
        #pragma unroll
        for (int k = 0; k < M; k++) acc = fmaf(sInst[p * M + k], emb_w[k * D + d], acc);
        sE[i] = acc;
    }
    __syncthreads();

    if (t < D) {
        float s = 0.f, q = 0.f;
        for (int p = 0; p < P_INST; p++) { float v = sE[p * D + t]; s += v; q += v * v; }
        float mu = s * (1.f / P_INST);
        float var = q * (1.f / P_INST) - mu * mu;
        float a = emb_g[t] * rsqrtf(var + 1e-5f);
        sA[t] = a;
        sC[t] = emb_b[t] - mu * a;
    }
    __syncthreads();

    for (int i = t; i < P_INST * D; i += 256) {
        int d = i & (D - 1);
        sE[i] = fmaxf(sE[i] * sA[d] + sC[d], 0.f);
    }
    __syncthreads();

    for (int i = t; i < P_INST * NP; i += 256) {
        int p = i / NP, q = i - p * NP;
        float acc = ctrl_b[q];
        #pragma unroll
        for (int d = 0; d < D; d++) acc = fmaf(sE[p * D + d], sCW[d * NP + q], acc);
        params[i] = acc;
    }
    __threadfence_block();
    __syncthreads();

    int lane = t & 63, wv = t >> 6;
    int row = lane & 15, kbase = (lane >> 4) * 8;
    for (int p = wv; p < P_INST; p += 4) {
        const float* pp = params + p * NP;
        unsigned int w[4];
        #pragma unroll
        for (int i = 0; i < 4; i++) {
            unsigned short lo = 0, hi = 0;
            #pragma unroll
            for (int h = 0; h < 2; h++) {
                int k = kbase + 2 * i + h;
                float v;
                if (k < 19) v = pp[row * 19 + k];
                else if (k == 19)
                    v = pp[320 + row] - (centers[p * 3 + 0] * pp[row * 19 + 0]
                                       + centers[p * 3 + 1] * pp[row * 19 + 1]
                                       + centers[p * 3 + 2] * pp[row * 19 + 2]);
                else v = 0.f;
                if (h == 0) lo = f2bf(v); else hi = f2bf(v);
            }
            w[i] = (unsigned)lo | ((unsigned)hi << 16);
        }
        uint4* dst = (uint4*)((char*)apackf + (size_t)p * 1024 + lane * 16);
        *dst = make_uint4(w[0], w[1], w[2], w[3]);
        if (lane < 16) w2p[p * 16 + lane] = pp[304 + lane];
        if (lane == 0) b2p[p] = pp[336];
    }
}

// ---------------------------------------------------------------------------
// One MLP layer fused with output stats: (optional BN+relu of prev) then
// x @ W -> ybuf, plus block-level sum/sumsq of y via LDS transpose.
// ---------------------------------------------------------------------------
template <int L>
__global__ __launch_bounds__(BLK) void k_layer(
    const float* __restrict__ feats, const float* __restrict__ W,
    const float* __restrict__ stats, float* __restrict__ ybuf,
    float* __restrict__ partials)
{
    __shared__ float tr[256 * 33];      // padded transpose buffer
    __shared__ float red2[2][8][32];
    int t = threadIdx.x;
    int n = blockIdx.x * BLK + t;
    bool valid = n < N_PTS;
    int nc = valid ? n : N_PTS - 1;

    const float* src = (L == 0) ? (feats + (size_t)nc * M) : (ybuf + (size_t)nc * M);
    float x[M];
    #pragma unroll
    for (int q = 0; q < M / 4; q++) {
        float4 v = ((const float4*)src)[q];
        x[4*q] = v.x; x[4*q+1] = v.y; x[4*q+2] = v.z; x[4*q+3] = v.w;
    }
    if (L > 0) {
        const float* st = stats + (L - 1) * 64;
        #pragma unroll
        for (int j = 0; j < M; j++) x[j] = fmaxf(fmaf(x[j], st[j], st[32 + j]), 0.f);
    }
    float y[M];
    #pragma unroll
    for (int j = 0; j < M; j++) y[j] = 0.f;
    #pragma unroll
    for (int i = 0; i < M; i++) {
        float xi = x[i];
        #pragma unroll
        for (int j = 0; j < M; j++) y[j] = fmaf(xi, W[i * M + j], y[j]);
    }
    if (valid) {
        float4* dst = (float4*)(ybuf + (size_t)n * M);
        #pragma unroll
        for (int q = 0; q < M / 4; q++)
            dst[q] = make_float4(y[4*q], y[4*q+1], y[4*q+2], y[4*q+3]);
    } else {
        #pragma unroll
        for (int j = 0; j < M; j++) y[j] = 0.f;
    }

    // block reduction: transpose rows -> per-channel sums
    #pragma unroll
    for (int j = 0; j < M; j++) tr[t * 33 + j] = y[j];
    __syncthreads();
    int c = t & 31, s = t >> 5;
    float S = 0.f, Q = 0.f;
    #pragma unroll
    for (int r = 0; r < 32; r++) {
        float v = tr[(s * 32 + r) * 33 + c];
        S += v; Q += v * v;
    }
    red2[0][s][c] = S;
    red2[1][s][c] = Q;
    __syncthreads();
    if (t < 64) {
        int cc = t & 31, k = t >> 5;
        float a = 0.f;
        #pragma unroll
        for (int sl = 0; sl < 8; sl++) a += red2[k][sl][cc];
        partials[(size_t)blockIdx.x * 64 + k * 32 + cc] = a;
    }
}

// ---------------------------------------------------------------------------
// Parallel reduce: block c handles channel c; 128 threads sum, 128 sumsq
// ---------------------------------------------------------------------------
__global__ __launch_bounds__(256) void k_reduce(
    const float* __restrict__ partials,
    const float* __restrict__ g, const float* __restrict__ b,
    float* __restrict__ stats_out)
{
    int c = blockIdx.x;          // 0..31
    int t = threadIdx.x;
    int part = t >> 7;           // 0: sum, 1: sumsq
    int i0 = t & 127;
    float s = 0.f;
    for (int i = i0; i < NB; i += 128)
        s += partials[(size_t)i * 64 + part * 32 + c];
    __shared__ float sh[256];
    sh[t] = s;
    __syncthreads();
    #pragma unroll
    for (int off = 64; off; off >>= 1) {
        if ((t & 127) < off) sh[t] += sh[t + off];
        __syncthreads();
    }
    if (t == 0) {
        float S = sh[0], Q = sh[128];
        float mu = S * (1.f / N_PTS);
        float var = Q * (1.f / N_PTS) - mu * mu;
        float a = g[c] * rsqrtf(var + 1e-5f);
        stats_out[c] = a;
        stats_out[32 + c] = b[c] - mu * a;
    }
}

// ---------------------------------------------------------------------------
// Fused head: BN3+relu -> mask_feats -> Z pack (LDS) -> per-p MFMA,
// relu·w2 dot, full-wave 64-lane store.
// Block: 256 threads = 4 waves; 128 points. wave = (slab, phalf):
//   slab  = wv&1  -> 64-point group, phalf = wv>>1 -> 32 p's.
// ---------------------------------------------------------------------------
__global__ __launch_bounds__(BLK) void k_head(
    const float* __restrict__ ybuf, const float* __restrict__ coords,
    const float* __restrict__ w_out, const float* __restrict__ b_out,
    const float* __restrict__ stats, const float* __restrict__ w2p,
    const float* __restrict__ b2p, const float* __restrict__ apackf,
    float* __restrict__ out)
{
    __shared__ unsigned int zlds[HPB * 20];   // 80B stride per point
    int t = threadIdx.x;
    int nblk = blockIdx.x * HPB;

    if (t < HPB) {
        int nc = nblk + t;
        if (nc >= N_PTS) nc = N_PTS - 1;
        const float* yr = ybuf + (size_t)nc * M;
        float x[M];
        #pragma unroll
        for (int q = 0; q < M / 4; q++) {
            float4 v = ((const float4*)yr)[q];
            x[4*q] = v.x; x[4*q+1] = v.y; x[4*q+2] = v.z; x[4*q+3] = v.w;
        }
        const float* st = stats + 128;
        #pragma unroll
        for (int j = 0; j < M; j++) x[j] = fmaxf(fmaf(x[j], st[j], st[32 + j]), 0.f);

        float mf[D];
        #pragma unroll
        for (int d = 0; d < D; d++) mf[d] = b_out[d];
        #pragma unroll
        for (int i = 0; i < M; i++) {
            float xi = x[i];
            #pragma unroll
            for (int d = 0; d < D; d++) mf[d] = fmaf(xi, w_out[i * D + d], mf[d]);
        }
        float z[20];
        z[0] = coords[(size_t)nc * 3 + 0];
        z[1] = coords[(size_t)nc * 3 + 1];
        z[2] = coords[(size_t)nc * 3 + 2];
        #pragma unroll
        for (int d = 0; d < D; d++) z[3 + d] = mf[d];
        z[19] = 1.0f;

        unsigned int zw[16];
        #pragma unroll
        for (int i = 0; i < 10; i++)
            zw[i] = (unsigned)f2bf(z[2 * i]) | ((unsigned)f2bf(z[2 * i + 1]) << 16);
        #pragma unroll
        for (int i = 10; i < 16; i++) zw[i] = 0u;
        uint4* zd = (uint4*)&zlds[t * 20];
        #pragma unroll
        for (int i = 0; i < 4; i++)
            zd[i] = make_uint4(zw[4*i], zw[4*i+1], zw[4*i+2], zw[4*i+3]);
    }
    __syncthreads();

    int lane = t & 63, wv = t >> 6;
    int slab = wv & 1, phalf = wv >> 1;
    int cl = lane & 15, kg = lane >> 4;
    int n0 = nblk + slab * 64;
    int nn = n0 + lane;
    bool wr = nn < N_PTS;

    short8v b8[4];
    #pragma unroll
    for (int s = 0; s < 4; s++)
        b8[s] = *(const short8v*)&zlds[(slab * 64 + s * 16 + cl) * 20 + kg * 4];

    const char* abase = (const char*)apackf + (size_t)(phalf * 32) * 1024 + lane * 16;

    #pragma unroll 4
    for (int i = 0; i < 32; i++) {
        int p = phalf * 32 + i;
        short8v a8 = *(const short8v*)(abase + (size_t)i * 1024);
        floatx4 w2v = *(const floatx4*)(w2p + p * 16 + kg * 4);
        float b2 = b2p[p];

        float vs[4];
        #pragma unroll
        for (int s = 0; s < 4; s++) {
            floatx4 acc = {0.f, 0.f, 0.f, 0.f};
            acc = __builtin_amdgcn_mfma_f32_16x16x32_bf16(a8, b8[s], acc, 0, 0, 0);
            float v = fmaxf(acc[0], 0.f) * w2v[0];
            v = fmaf(fmaxf(acc[1], 0.f), w2v[1], v);
            v = fmaf(fmaxf(acc[2], 0.f), w2v[2], v);
            v = fmaf(fmaxf(acc[3], 0.f), w2v[3], v);
            v += __shfl_xor(v, 16, 64);
            v += __shfl_xor(v, 32, 64);   // now replicated across all lanes
            vs[s] = v;
        }
        float vout = (kg == 0) ? vs[0] : (kg == 1) ? vs[1] : (kg == 2) ? vs[2] : vs[3];
        if (wr) out[(size_t)p * N_PTS + nn] = vout + b2;
    }
}

// ---------------------------------------------------------------------------
extern "C" void kernel_launch(void* const* d_in, const int* in_sizes, int n_in,
                              void* d_out, int out_size, void* d_ws, size_t ws_size,
                              hipStream_t stream) {
    const float* feats   = (const float*)d_in[0];
    const float* coords  = (const float*)d_in[1];
    const float* inst    = (const float*)d_in[2];
    const float* centers = (const float*)d_in[3];
    const float* mw1 = (const float*)d_in[4];
    const float* mg1 = (const float*)d_in[5];
    const float* mb1 = (const float*)d_in[6];
    const float* mw2 = (const float*)d_in[7];
    const float* mg2 = (const float*)d_in[8];
    const float* mb2 = (const float*)d_in[9];
    const float* mw3 = (const float*)d_in[10];
    const float* mg3 = (const float*)d_in[11];
    const float* mb3 = (const float*)d_in[12];
    const float* wout = (const float*)d_in[13];
    const float* bout = (const float*)d_in[14];
    const float* embw = (const float*)d_in[15];
    const float* embg = (const float*)d_in[16];
    const float* embb = (const float*)d_in[17];
    const float* cw   = (const float*)d_in[18];
    const float* cb   = (const float*)d_in[19];

    float* wsf      = (float*)d_ws;
    float* params   = wsf + WS_PARAMS;
    float* stats    = wsf + WS_STATS;
    float* w2p      = wsf + WS_W2;
    float* b2p      = wsf + WS_B2;
    float* apackf   = wsf + WS_APACK;
    float* partials = wsf + WS_PART;
    float* ybuf     = wsf + WS_Y;
    float* out      = (float*)d_out;

    k_prep<<<1, 256, 0, stream>>>(inst, embw, embg, embb, cw, cb, centers,
                                  params, apackf, w2p, b2p);

    k_layer<0><<<NB, BLK, 0, stream>>>(feats, mw1, stats, ybuf, partials);
    k_reduce<<<32, 256, 0, stream>>>(partials, mg1, mb1, stats + 0);

    k_layer<1><<<NB, BLK, 0, stream>>>(feats, mw2, stats, ybuf, partials);
    k_reduce<<<32, 256, 0, stream>>>(partials, mg2, mb2, stats + 64);

    k_layer<2><<<NB, BLK, 0, stream>>>(feats, mw3, stats, ybuf, partials);
    k_reduce<<<32, 256, 0, stream>>>(partials, mg3, mb3, stats + 128);

    k_head<<<NBH, BLK, 0, stream>>>(ybuf, coords, wout, bout, stats,
                                    w2p, b2p, apackf, out);
}